// Round 7
// baseline (1732.299 us; speedup 1.0000x reference)
//
#include <hip/hip_runtime.h>
#include <stdint.h>
#include <stddef.h>

// Problem dims
#define B_  128
#define S_  48
#define E_  620
#define EP  640    // E padded to multiple of 32 (zeros)
#define H_  2400
#define N3  7200   // 3*H (r,i,n concatenated)
#define KH  2400
#define P1_ITERS 20  // phase-1 K = 640 = 20 x 32
#define P2_ITERS 75  // phase-2 K = 2400 = 75 x 32
#define KW_ITERS 25  // per-wave k-iters (3-way K split)
#define RING 8       // ring depth (40 loads in flight/wave, ~640 cy cover)
#define GBLK 150     // H_/16 hidden-unit groups = grid of phase 2
// Packed-chunk geometry (halves): one (g,kt,plane) chunk = 16 rows x 32 k
#define WCHUNK 512           // halves per plane-chunk (1024 B)
#define WITER  (3 * WCHUNK)  // halves per k-iter per block (3 planes)
#define WBLK   (P2_ITERS * WITER)  // halves per block's full weight stream
#define ACHUNK (B_ * 32)     // halves per k-iter of packed A (128 rows x 32 k)
#define XSLICES 8            // gemm_x m-slices (counter visibility for gemm_gate)

typedef _Float16 half_t;
typedef __attribute__((ext_vector_type(8))) _Float16 half8;
typedef __attribute__((ext_vector_type(4))) float    floatx4;

// Workgroup barrier that waits ONLY on LDS ops; in-flight global loads keep
// flying. 0xC07F = vmcnt(63) expcnt(7) lgkmcnt(0).  (phase-1 only)
__device__ __forceinline__ void lds_barrier() {
  __builtin_amdgcn_sched_barrier(0);
  __builtin_amdgcn_s_waitcnt(0xC07F);
  __builtin_amdgcn_s_barrier();
  __builtin_amdgcn_sched_barrier(0);
}

// ---- x = fp16(emb[tokens]), padded [6144, 640] ----
__global__ void gather_cast_x(const int* __restrict__ tokens,
                              const float* __restrict__ emb,
                              half_t* __restrict__ xb) {
  int idx = blockIdx.x * 256 + threadIdx.x;       // over 6144*EP
  int m = idx / EP, c = idx - m * EP;
  float v = 0.f;
  if (c < E_) v = emb[(size_t)tokens[m] * E_ + c];
  xb[idx] = (half_t)v;
}

// ---- W_i = fp16 concat(W_ir,W_ii,W_in) [7200, 640]; bias concat [7200] ----
__global__ void convert_wi(const float* __restrict__ Wir, const float* __restrict__ Wii,
                           const float* __restrict__ Win,
                           const float* __restrict__ bir, const float* __restrict__ bii,
                           const float* __restrict__ bin,
                           half_t* __restrict__ Wi, float* __restrict__ bias) {
  int idx = blockIdx.x * 256 + threadIdx.x;       // over N3*EP
  int r = idx / EP, c = idx - r * EP;
  const float* W = (r < H_) ? Wir : (r < 2*H_ ? Wii : Win);
  int rr = (r < H_) ? r : (r < 2*H_ ? r - H_ : r - 2*H_);
  float v = (c < E_) ? W[(size_t)rr * E_ + c] : 0.f;
  Wi[idx] = (half_t)v;
  if (c == 0) {
    const float* bb = (r < H_) ? bir : (r < 2*H_ ? bii : bin);
    bias[r] = bb[rr];
  }
}

// ---- Wp = fp16 PACKED recurrent weights ----
// Layout: Wp[g][kt][plane][fm(16)][ksub(32)]; one chunk = 1024 B = exactly
// one wave's contiguous MFMA B-frag load (the round-4->5 TA fix).
__global__ void convert_wh(const float* __restrict__ Whr, const float* __restrict__ Whi,
                           const float* __restrict__ Whn, half_t* __restrict__ Wp) {
  int idx = blockIdx.x * 256 + threadIdx.x;       // over N3*KH
  int r3 = idx / KH, c = idx - r3 * KH;
  const float* W = (r3 < H_) ? Whr : (r3 < 2*H_ ? Whi : Whn);
  int p  = (r3 < H_) ? 0 : (r3 < 2*H_ ? 1 : 2);
  int rr = r3 - p * H_;
  int g = rr >> 4, fm = rr & 15;
  int kt = c >> 5, ksub = c & 31;
  size_t dst = ((size_t)g * WBLK) + (size_t)kt * WITER + p * WCHUNK + fm * 32 + ksub;
  Wp[dst] = (half_t)W[(size_t)rr * KH + c];
}

__global__ void init_h(float* __restrict__ h, half_t* __restrict__ Ap) {
  int idx = blockIdx.x * 256 + threadIdx.x;       // over B_*H_
  h[idx] = 0.f;
  Ap[idx] = (half_t)0.f;
}

// ---- Phase 1: gx = fp16( xb @ Wi^T + bias )  [6144 x 7200], K=640 ----
// (r5/r6 structure: 128x128 tile, frag-major LDS dbuf, lgkm-only barrier.)
// Sliced along M (mblk0 = slice base) so each dispatch is ~16 us and the
// rocprof top-5 surfaces gemm_gate instead of 5 copies of this kernel.
__global__ __launch_bounds__(256, 2) void gemm_x(
    const half_t* __restrict__ A,   // xb [6144 x 640]
    const half_t* __restrict__ Bm,  // Wi [7200 x 640]
    half_t* __restrict__ C,         // gx [6144 x 7200]
    const float* __restrict__ bias,
    int mblk0)
{
  __shared__ half_t As[2][4096];
  __shared__ half_t Bs[2][4096];

  const int tid = threadIdx.x;
  const int lane = tid & 63;
  const int w = tid >> 6;
  const int m0 = (mblk0 + blockIdx.x) * 128;
  const int n0 = blockIdx.y * 128;
  const int wm = (w >> 1) * 64, wn = (w & 1) * 64;

  const int c0 = tid, c1 = tid + 256;
  const int rA0 = m0 + (c0 >> 6) * 16 + (c0 & 15), q0 = ((c0 >> 4) & 3) * 8;
  const int rA1 = m0 + (c1 >> 6) * 16 + (c1 & 15), q1 = ((c1 >> 4) & 3) * 8;
  int rB0 = n0 + (c0 >> 6) * 16 + (c0 & 15); if (rB0 >= N3) rB0 = N3 - 1;
  int rB1 = n0 + (c1 >> 6) * 16 + (c1 & 15); if (rB1 >= N3) rB1 = N3 - 1;
  const half_t* pA0 = A  + (size_t)rA0 * EP + q0;
  const half_t* pA1 = A  + (size_t)rA1 * EP + q1;
  const half_t* pB0 = Bm + (size_t)rB0 * EP + q0;
  const half_t* pB1 = Bm + (size_t)rB1 * EP + q1;

  floatx4 acc[4][4] = {};

  half8 ga0 = *(const half8*)(pA0);
  half8 ga1 = *(const half8*)(pA1);
  half8 gb0 = *(const half8*)(pB0);
  half8 gb1 = *(const half8*)(pB1);
  *(half8*)(As[0] + c0 * 8) = ga0;
  *(half8*)(As[0] + c1 * 8) = ga1;
  *(half8*)(Bs[0] + c0 * 8) = gb0;
  *(half8*)(Bs[0] + c1 * 8) = gb1;
  ga0 = *(const half8*)(pA0 + 32);
  ga1 = *(const half8*)(pA1 + 32);
  gb0 = *(const half8*)(pB0 + 32);
  gb1 = *(const half8*)(pB1 + 32);
  lds_barrier();

  #pragma unroll
  for (int i = 0; i < P1_ITERS; ++i) {
    const int cur = i & 1, nxt = cur ^ 1;
    half8 a[4], b[4];
    #pragma unroll
    for (int f = 0; f < 4; ++f) {
      a[f] = *(const half8*)(As[cur] + (((wm >> 4) + f) * 64 + lane) * 8);
      b[f] = *(const half8*)(Bs[cur] + (((wn >> 4) + f) * 64 + lane) * 8);
    }
    if (i + 1 < P1_ITERS) {
      *(half8*)(As[nxt] + c0 * 8) = ga0;
      *(half8*)(As[nxt] + c1 * 8) = ga1;
      *(half8*)(Bs[nxt] + c0 * 8) = gb0;
      *(half8*)(Bs[nxt] + c1 * 8) = gb1;
    }
    if (i + 2 < P1_ITERS) {
      int ko = (i + 2) * 32;
      ga0 = *(const half8*)(pA0 + ko);
      ga1 = *(const half8*)(pA1 + ko);
      gb0 = *(const half8*)(pB0 + ko);
      gb1 = *(const half8*)(pB1 + ko);
    }
    #pragma unroll
    for (int mf = 0; mf < 4; ++mf)
      #pragma unroll
      for (int nf = 0; nf < 4; ++nf)
        acc[mf][nf] = __builtin_amdgcn_mfma_f32_16x16x32_f16(
            a[mf], b[nf], acc[mf][nf], 0, 0, 0);
    if (i + 1 < P1_ITERS) lds_barrier();
  }

  const int col = lane & 15, qr = (lane >> 4) * 4;
  #pragma unroll
  for (int nf = 0; nf < 4; ++nf) {
    int n = n0 + wn + nf * 16 + col;
    if (n >= N3) continue;
    float bv = bias[n];
    #pragma unroll
    for (int mf = 0; mf < 4; ++mf)
      #pragma unroll
      for (int r = 0; r < 4; ++r)
        C[(size_t)(m0 + wm + mf * 16 + qr + r) * N3 + n] =
            (half_t)(acc[mf][nf][r] + bv);
  }
}

// ---- Phase 2: one kernel/step, block-local, packed operands, 12 waves. ----
// Round-6 structure (passed, best) with RING 5 -> 8: 40 loads in flight per
// wave to cover the suspected L3-hit latency (Wf slice/XCD = 4.37 MB > 4 MiB
// L2 -> evicts between steps -> every step streams 34.6 MB from L3).
// 768 threads = 12 waves = (kw in {0,1,2}) x (mw in {0..3}); wave (kw,mw)
// does 25 k-iters for batch stripe 32*mw. kw=1,2 dump fp32 partials to LDS;
// one barrier; kw=0 sums and runs the per-lane gate epilogue.
__global__ __launch_bounds__(768, 3) void gemm_gate(
    const half_t* __restrict__ Ap_old,  // packed hh [75][128][32]
    const half_t* __restrict__ Wp,      // packed weights [150][75][3][512]
    const half_t* __restrict__ gx,      // [6144 x 7200]
    const float* __restrict__ hold,     // h_old  [128 x 2400] fp32
    float* __restrict__ hnew,
    half_t* __restrict__ Ap_new,        // packed hh out
    const int* __restrict__ lengths,
    float* __restrict__ out,
    int t)
{
  __shared__ floatx4 red[2][4][6][64];   // 48 KB partials (kw=1,2)

  const int tid  = threadIdx.x;
  const int lane = tid & 63;
  const int w    = tid >> 6;        // 0..11
  const int mw   = w & 3;           // batch stripe
  const int kw   = w >> 2;          // k-slice 0..2
  const int g    = blockIdx.x;      // 0..149
  const int wm   = mw * 32;

  const int fm = lane & 15;         // frag row within 16
  const int fk = (lane >> 4) * 8;   // frag k-offset

  const half_t* pW = Wp + (size_t)g * WBLK + (size_t)kw * KW_ITERS * WITER
                        + fm * 32 + fk;
  const half_t* pA = Ap_old + (size_t)kw * KW_ITERS * ACHUNK
                            + (wm + fm) * 32 + fk;

  floatx4 acc[2][3] = {};   // [mf][plane]

  half8 aR[RING][2];
  half8 bR[RING][3];
  #pragma unroll
  for (int d = 0; d < RING; ++d) {
    aR[d][0] = *(const half8*)(pA + d * ACHUNK);
    aR[d][1] = *(const half8*)(pA + d * ACHUNK + 512);
    bR[d][0] = *(const half8*)(pW + d * WITER);
    bR[d][1] = *(const half8*)(pW + d * WITER + WCHUNK);
    bR[d][2] = *(const half8*)(pW + d * WITER + 2 * WCHUNK);
  }

  #pragma unroll
  for (int i = 0; i < KW_ITERS; ++i) {
    const int s = i % RING;
    half8 a0 = aR[s][0], a1 = aR[s][1];
    half8 br = bR[s][0], bi = bR[s][1], bn = bR[s][2];
    if (i + RING < KW_ITERS) {
      aR[s][0] = *(const half8*)(pA + (i + RING) * ACHUNK);
      aR[s][1] = *(const half8*)(pA + (i + RING) * ACHUNK + 512);
      bR[s][0] = *(const half8*)(pW + (i + RING) * WITER);
      bR[s][1] = *(const half8*)(pW + (i + RING) * WITER + WCHUNK);
      bR[s][2] = *(const half8*)(pW + (i + RING) * WITER + 2 * WCHUNK);
    }
    acc[0][0] = __builtin_amdgcn_mfma_f32_16x16x32_f16(a0, br, acc[0][0], 0, 0, 0);
    acc[1][0] = __builtin_amdgcn_mfma_f32_16x16x32_f16(a1, br, acc[1][0], 0, 0, 0);
    acc[0][1] = __builtin_amdgcn_mfma_f32_16x16x32_f16(a0, bi, acc[0][1], 0, 0, 0);
    acc[1][1] = __builtin_amdgcn_mfma_f32_16x16x32_f16(a1, bi, acc[1][1], 0, 0, 0);
    acc[0][2] = __builtin_amdgcn_mfma_f32_16x16x32_f16(a0, bn, acc[0][2], 0, 0, 0);
    acc[1][2] = __builtin_amdgcn_mfma_f32_16x16x32_f16(a1, bn, acc[1][2], 0, 0, 0);
  }

  // K-split reduction: kw=1,2 publish partials, kw=0 sums.
  if (kw != 0) {
    #pragma unroll
    for (int mf = 0; mf < 2; ++mf)
      #pragma unroll
      for (int p = 0; p < 3; ++p)
        red[kw - 1][mw][mf * 3 + p][lane] = acc[mf][p];
  }
  __syncthreads();
  if (kw != 0) return;

  #pragma unroll
  for (int mf = 0; mf < 2; ++mf)
    #pragma unroll
    for (int p = 0; p < 3; ++p)
      acc[mf][p] += red[0][mw][mf * 3 + p][lane] + red[1][mw][mf * 3 + p][lane];

  // Per-lane gate epilogue. C-layout: col = lane&15 (unit),
  // row = batch = wm + mf*16 + (lane>>4)*4 + r  (verified in baseline).
  const int j  = g * 16 + (lane & 15);
  const int jb = (j >> 5) * ACHUNK + (j & 31);   // packed-A dest base
  const int qr = (lane >> 4) * 4;
  #pragma unroll
  for (int mf = 0; mf < 2; ++mf) {
    #pragma unroll
    for (int r = 0; r < 4; ++r) {
      const int b = wm + mf * 16 + qr + r;
      const size_t rx = ((size_t)b * S_ + t) * N3 + j;
      const float xr = (float)gx[rx];
      const float xi = (float)gx[rx + H_];
      const float xn = (float)gx[rx + 2 * H_];
      const float ho = hold[(size_t)b * H_ + j];
      const float rg = 1.f / (1.f + __expf(-(xr + acc[mf][0][r])));
      const float ig = 1.f / (1.f + __expf(-(xi + acc[mf][1][r])));
      const float ta = xn + rg * acc[mf][2][r];
      const float nn = 1.f - 2.f / (1.f + __expf(2.f * ta));  // tanh(ta)
      const float hv = (1.f - ig) * nn + ig * ho;
      hnew[(size_t)b * H_ + j] = hv;
      Ap_new[jb + b * 32]      = (half_t)hv;
      int lc = lengths[b] - 1;
      lc = lc < 0 ? 0 : (lc > S_ - 1 ? S_ - 1 : lc);
      if (t == lc) out[(size_t)b * H_ + j] = hv;
    }
  }
}

extern "C" void kernel_launch(void* const* d_in, const int* in_sizes, int n_in,
                              void* d_out, int out_size, void* d_ws, size_t ws_size,
                              hipStream_t stream)
{
  const int*   tokens  = (const int*)d_in[0];
  const int*   lengths = (const int*)d_in[1];
  const float* emb = (const float*)d_in[2];
  const float* Wir = (const float*)d_in[3];
  const float* Wii = (const float*)d_in[4];
  const float* Win = (const float*)d_in[5];
  const float* bir = (const float*)d_in[6];
  const float* bii = (const float*)d_in[7];
  const float* bin = (const float*)d_in[8];
  const float* Whr = (const float*)d_in[9];
  const float* Whi = (const float*)d_in[10];
  const float* Whn = (const float*)d_in[11];
  float* out = (float*)d_out;

  char* ws = (char*)d_ws;
  size_t off = 0;
  auto alloc = [&](size_t bytes) {
    void* p = ws + off;
    off = (off + bytes + 255) & ~(size_t)255;
    return p;
  };
  half_t* xb   = (half_t*)alloc((size_t)(B_ * S_) * EP * 2);   //  7.9 MB
  half_t* Wi   = (half_t*)alloc((size_t)N3 * EP * 2);          //  9.2 MB
  half_t* Wp   = (half_t*)alloc((size_t)GBLK * WBLK * 2);      // 34.6 MB packed
  float*  bias = (float*)alloc((size_t)N3 * 4);
  half_t* gx   = (half_t*)alloc((size_t)(B_ * S_) * N3 * 2);   // 88.5 MB
  float*  h0   = (float*)alloc((size_t)B_ * H_ * 4);           // ping-pong h
  float*  h1   = (float*)alloc((size_t)B_ * H_ * 4);
  half_t* Ap0  = (half_t*)alloc((size_t)B_ * H_ * 2);          // packed hh
  half_t* Ap1  = (half_t*)alloc((size_t)B_ * H_ * 2);

  gather_cast_x<<<(B_ * S_ * EP) / 256, 256, 0, stream>>>(tokens, emb, xb);
  convert_wi<<<(N3 * EP) / 256, 256, 0, stream>>>(Wir, Wii, Win, bir, bii, bin, Wi, bias);
  convert_wh<<<(N3 * KH) / 256, 256, 0, stream>>>(Whr, Whi, Whn, Wp);
  init_h<<<(B_ * H_) / 256, 256, 0, stream>>>(h0, Ap0);

  // Phase 1: gates_x, sliced 8x along M (48 m-blocks / 8 = 6 per slice) so
  // gemm_gate surfaces in the rocprof top-5 dispatches.
  for (int s = 0; s < XSLICES; ++s)
    gemm_x<<<dim3(48 / XSLICES, 57), 256, 0, stream>>>(xb, Wi, gx, bias,
                                                       s * (48 / XSLICES));

  // Phase 2: 48 GRU steps, one block-local fused dispatch each (12 waves)
  for (int t = 0; t < S_; ++t) {
    const half_t* ai = (t & 1) ? Ap1 : Ap0;
    half_t*       aw = (t & 1) ? Ap0 : Ap1;
    const float*  ho = (t & 1) ? h1  : h0;
    float*        hn = (t & 1) ? h0  : h1;
    gemm_gate<<<dim3(GBLK), 768, 0, stream>>>(
        ai, Wp, gx, ho, hn, aw, lengths, out, t);
  }
}

// Round 8
// 1721.887 us; speedup vs baseline: 1.0060x; 1.0060x over previous
//
#include <hip/hip_runtime.h>
#include <stdint.h>
#include <stddef.h>

// Problem dims
#define B_  128
#define S_  48
#define E_  620
#define EP  640    // E padded to multiple of 32 (zeros)
#define H_  2400
#define N3  7200   // 3*H (r,i,n concatenated)
#define KH  2400
#define P1_ITERS 20  // phase-1 K = 640 = 20 x 32
#define P2_ITERS 75  // phase-2 K = 2400 = 75 x 32
#define KW_ITERS 25  // per-wave k-iters (3-way K split)
#define RING 5       // ring depth (RING 8 spilled under the 3-wave bound; reverted)
#define GBLK 150     // H_/16 hidden-unit groups = grid of phase 2
// Packed-chunk geometry (halves): one (g,kt,plane) chunk = 16 rows x 32 k
#define WCHUNK 512           // halves per plane-chunk (1024 B)
#define WITER  (3 * WCHUNK)  // halves per k-iter per block (3 planes)
#define WBLK   (P2_ITERS * WITER)  // halves per block's full weight stream
#define ACHUNK (B_ * 32)     // halves per k-iter of packed A (128 rows x 32 k)
#define XSLICES 8            // gemm_x m-slices  (visibility: keep every
#define WSLICES 3            // convert_wh slices  non-recurrent dispatch <20us)

typedef _Float16 half_t;
typedef __attribute__((ext_vector_type(8))) _Float16 half8;
typedef __attribute__((ext_vector_type(4))) float    floatx4;

// Workgroup barrier that waits ONLY on LDS ops; in-flight global loads keep
// flying. 0xC07F = vmcnt(63) expcnt(7) lgkmcnt(0).  (phase-1 only)
__device__ __forceinline__ void lds_barrier() {
  __builtin_amdgcn_sched_barrier(0);
  __builtin_amdgcn_s_waitcnt(0xC07F);
  __builtin_amdgcn_s_barrier();
  __builtin_amdgcn_sched_barrier(0);
}

// ---- x = fp16(emb[tokens]), padded [6144, 640] ----
__global__ void gather_cast_x(const int* __restrict__ tokens,
                              const float* __restrict__ emb,
                              half_t* __restrict__ xb) {
  int idx = blockIdx.x * 256 + threadIdx.x;       // over 6144*EP
  int m = idx / EP, c = idx - m * EP;
  float v = 0.f;
  if (c < E_) v = emb[(size_t)tokens[m] * E_ + c];
  xb[idx] = (half_t)v;
}

// ---- W_i = fp16 concat(W_ir,W_ii,W_in) [7200, 640]; bias concat [7200] ----
__global__ void convert_wi(const float* __restrict__ Wir, const float* __restrict__ Wii,
                           const float* __restrict__ Win,
                           const float* __restrict__ bir, const float* __restrict__ bii,
                           const float* __restrict__ bin,
                           half_t* __restrict__ Wi, float* __restrict__ bias) {
  int idx = blockIdx.x * 256 + threadIdx.x;       // over N3*EP
  int r = idx / EP, c = idx - r * EP;
  const float* W = (r < H_) ? Wir : (r < 2*H_ ? Wii : Win);
  int rr = (r < H_) ? r : (r < 2*H_ ? r - H_ : r - 2*H_);
  float v = (c < E_) ? W[(size_t)rr * E_ + c] : 0.f;
  Wi[idx] = (half_t)v;
  if (c == 0) {
    const float* bb = (r < H_) ? bir : (r < 2*H_ ? bii : bin);
    bias[r] = bb[rr];
  }
}

// ---- Wp = fp16 PACKED recurrent weights ----
// Layout: Wp[g][kt][plane][fm(16)][ksub(32)]; one chunk = 1024 B = exactly
// one wave's contiguous MFMA B-frag load (the round-4->5 TA fix).
// Sliced 3x along rows for rocprof visibility (each ~16 us < gemm_gate).
__global__ void convert_wh(const float* __restrict__ Whr, const float* __restrict__ Whi,
                           const float* __restrict__ Whn, half_t* __restrict__ Wp,
                           int base) {
  int idx = base + blockIdx.x * 256 + threadIdx.x;   // over N3*KH
  int r3 = idx / KH, c = idx - r3 * KH;
  const float* W = (r3 < H_) ? Whr : (r3 < 2*H_ ? Whi : Whn);
  int p  = (r3 < H_) ? 0 : (r3 < 2*H_ ? 1 : 2);
  int rr = r3 - p * H_;
  int g = rr >> 4, fm = rr & 15;
  int kt = c >> 5, ksub = c & 31;
  size_t dst = ((size_t)g * WBLK) + (size_t)kt * WITER + p * WCHUNK + fm * 32 + ksub;
  Wp[dst] = (half_t)W[(size_t)rr * KH + c];
}

__global__ void init_h(float* __restrict__ h, half_t* __restrict__ Ap) {
  int idx = blockIdx.x * 256 + threadIdx.x;       // over B_*H_
  h[idx] = 0.f;
  Ap[idx] = (half_t)0.f;
}

// ---- Phase 1: gx = fp16( xb @ Wi^T + bias )  [6144 x 7200], K=640 ----
// (r5/r6 structure: 128x128 tile, frag-major LDS dbuf, lgkm-only barrier.)
// Sliced along M so each dispatch is ~16 us (rocprof top-5 visibility).
__global__ __launch_bounds__(256, 2) void gemm_x(
    const half_t* __restrict__ A,   // xb [6144 x 640]
    const half_t* __restrict__ Bm,  // Wi [7200 x 640]
    half_t* __restrict__ C,         // gx [6144 x 7200]
    const float* __restrict__ bias,
    int mblk0)
{
  __shared__ half_t As[2][4096];
  __shared__ half_t Bs[2][4096];

  const int tid = threadIdx.x;
  const int lane = tid & 63;
  const int w = tid >> 6;
  const int m0 = (mblk0 + blockIdx.x) * 128;
  const int n0 = blockIdx.y * 128;
  const int wm = (w >> 1) * 64, wn = (w & 1) * 64;

  const int c0 = tid, c1 = tid + 256;
  const int rA0 = m0 + (c0 >> 6) * 16 + (c0 & 15), q0 = ((c0 >> 4) & 3) * 8;
  const int rA1 = m0 + (c1 >> 6) * 16 + (c1 & 15), q1 = ((c1 >> 4) & 3) * 8;
  int rB0 = n0 + (c0 >> 6) * 16 + (c0 & 15); if (rB0 >= N3) rB0 = N3 - 1;
  int rB1 = n0 + (c1 >> 6) * 16 + (c1 & 15); if (rB1 >= N3) rB1 = N3 - 1;
  const half_t* pA0 = A  + (size_t)rA0 * EP + q0;
  const half_t* pA1 = A  + (size_t)rA1 * EP + q1;
  const half_t* pB0 = Bm + (size_t)rB0 * EP + q0;
  const half_t* pB1 = Bm + (size_t)rB1 * EP + q1;

  floatx4 acc[4][4] = {};

  half8 ga0 = *(const half8*)(pA0);
  half8 ga1 = *(const half8*)(pA1);
  half8 gb0 = *(const half8*)(pB0);
  half8 gb1 = *(const half8*)(pB1);
  *(half8*)(As[0] + c0 * 8) = ga0;
  *(half8*)(As[0] + c1 * 8) = ga1;
  *(half8*)(Bs[0] + c0 * 8) = gb0;
  *(half8*)(Bs[0] + c1 * 8) = gb1;
  ga0 = *(const half8*)(pA0 + 32);
  ga1 = *(const half8*)(pA1 + 32);
  gb0 = *(const half8*)(pB0 + 32);
  gb1 = *(const half8*)(pB1 + 32);
  lds_barrier();

  #pragma unroll
  for (int i = 0; i < P1_ITERS; ++i) {
    const int cur = i & 1, nxt = cur ^ 1;
    half8 a[4], b[4];
    #pragma unroll
    for (int f = 0; f < 4; ++f) {
      a[f] = *(const half8*)(As[cur] + (((wm >> 4) + f) * 64 + lane) * 8);
      b[f] = *(const half8*)(Bs[cur] + (((wn >> 4) + f) * 64 + lane) * 8);
    }
    if (i + 1 < P1_ITERS) {
      *(half8*)(As[nxt] + c0 * 8) = ga0;
      *(half8*)(As[nxt] + c1 * 8) = ga1;
      *(half8*)(Bs[nxt] + c0 * 8) = gb0;
      *(half8*)(Bs[nxt] + c1 * 8) = gb1;
    }
    if (i + 2 < P1_ITERS) {
      int ko = (i + 2) * 32;
      ga0 = *(const half8*)(pA0 + ko);
      ga1 = *(const half8*)(pA1 + ko);
      gb0 = *(const half8*)(pB0 + ko);
      gb1 = *(const half8*)(pB1 + ko);
    }
    #pragma unroll
    for (int mf = 0; mf < 4; ++mf)
      #pragma unroll
      for (int nf = 0; nf < 4; ++nf)
        acc[mf][nf] = __builtin_amdgcn_mfma_f32_16x16x32_f16(
            a[mf], b[nf], acc[mf][nf], 0, 0, 0);
    if (i + 1 < P1_ITERS) lds_barrier();
  }

  const int col = lane & 15, qr = (lane >> 4) * 4;
  #pragma unroll
  for (int nf = 0; nf < 4; ++nf) {
    int n = n0 + wn + nf * 16 + col;
    if (n >= N3) continue;
    float bv = bias[n];
    #pragma unroll
    for (int mf = 0; mf < 4; ++mf)
      #pragma unroll
      for (int r = 0; r < 4; ++r)
        C[(size_t)(m0 + wm + mf * 16 + qr + r) * N3 + n] =
            (half_t)(acc[mf][nf][r] + bv);
  }
}

// ---- Phase 2: one kernel/step, block-local, packed operands, 12 waves. ----
// Round-6 proven structure (RING 5). h is stored TRANSPOSED [H][B] (private
// to init_h/gemm_gate) so the epilogue's h load/store is 2x dwordx4 per lane
// instead of 8 scalars at 9.6 KB stride.
// 768 threads = 12 waves = (kw in {0,1,2}) x (mw in {0..3}); wave (kw,mw)
// does 25 k-iters for batch stripe 32*mw. kw=1,2 dump fp32 partials to LDS;
// one barrier; kw=0 sums and runs the per-lane gate epilogue.
__global__ __launch_bounds__(768, 3) void gemm_gate(
    const half_t* __restrict__ Ap_old,  // packed hh [75][128][32]
    const half_t* __restrict__ Wp,      // packed weights [150][75][3][512]
    const half_t* __restrict__ gx,      // [6144 x 7200]
    const float* __restrict__ hold,     // h_old  [H][B] fp32 (transposed)
    float* __restrict__ hnew,           // h_new  [H][B]
    half_t* __restrict__ Ap_new,        // packed hh out
    const int* __restrict__ lengths,
    float* __restrict__ out,            // [B][H] final output
    int t)
{
  __shared__ floatx4 red[2][4][6][64];   // 48 KB partials (kw=1,2)

  const int tid  = threadIdx.x;
  const int lane = tid & 63;
  const int w    = tid >> 6;        // 0..11
  const int mw   = w & 3;           // batch stripe
  const int kw   = w >> 2;          // k-slice 0..2
  const int g    = blockIdx.x;      // 0..149
  const int wm   = mw * 32;

  const int fm = lane & 15;         // frag row within 16
  const int fk = (lane >> 4) * 8;   // frag k-offset

  const half_t* pW = Wp + (size_t)g * WBLK + (size_t)kw * KW_ITERS * WITER
                        + fm * 32 + fk;
  const half_t* pA = Ap_old + (size_t)kw * KW_ITERS * ACHUNK
                            + (wm + fm) * 32 + fk;

  floatx4 acc[2][3] = {};   // [mf][plane]

  half8 aR[RING][2];
  half8 bR[RING][3];
  #pragma unroll
  for (int d = 0; d < RING; ++d) {
    aR[d][0] = *(const half8*)(pA + d * ACHUNK);
    aR[d][1] = *(const half8*)(pA + d * ACHUNK + 512);
    bR[d][0] = *(const half8*)(pW + d * WITER);
    bR[d][1] = *(const half8*)(pW + d * WITER + WCHUNK);
    bR[d][2] = *(const half8*)(pW + d * WITER + 2 * WCHUNK);
  }

  #pragma unroll
  for (int i = 0; i < KW_ITERS; ++i) {
    const int s = i % RING;
    half8 a0 = aR[s][0], a1 = aR[s][1];
    half8 br = bR[s][0], bi = bR[s][1], bn = bR[s][2];
    if (i + RING < KW_ITERS) {
      aR[s][0] = *(const half8*)(pA + (i + RING) * ACHUNK);
      aR[s][1] = *(const half8*)(pA + (i + RING) * ACHUNK + 512);
      bR[s][0] = *(const half8*)(pW + (i + RING) * WITER);
      bR[s][1] = *(const half8*)(pW + (i + RING) * WITER + WCHUNK);
      bR[s][2] = *(const half8*)(pW + (i + RING) * WITER + 2 * WCHUNK);
    }
    acc[0][0] = __builtin_amdgcn_mfma_f32_16x16x32_f16(a0, br, acc[0][0], 0, 0, 0);
    acc[1][0] = __builtin_amdgcn_mfma_f32_16x16x32_f16(a1, br, acc[1][0], 0, 0, 0);
    acc[0][1] = __builtin_amdgcn_mfma_f32_16x16x32_f16(a0, bi, acc[0][1], 0, 0, 0);
    acc[1][1] = __builtin_amdgcn_mfma_f32_16x16x32_f16(a1, bi, acc[1][1], 0, 0, 0);
    acc[0][2] = __builtin_amdgcn_mfma_f32_16x16x32_f16(a0, bn, acc[0][2], 0, 0, 0);
    acc[1][2] = __builtin_amdgcn_mfma_f32_16x16x32_f16(a1, bn, acc[1][2], 0, 0, 0);
  }

  // K-split reduction: kw=1,2 publish partials, kw=0 sums.
  if (kw != 0) {
    #pragma unroll
    for (int mf = 0; mf < 2; ++mf)
      #pragma unroll
      for (int p = 0; p < 3; ++p)
        red[kw - 1][mw][mf * 3 + p][lane] = acc[mf][p];
  }
  __syncthreads();
  if (kw != 0) return;

  #pragma unroll
  for (int mf = 0; mf < 2; ++mf)
    #pragma unroll
    for (int p = 0; p < 3; ++p)
      acc[mf][p] += red[0][mw][mf * 3 + p][lane] + red[1][mw][mf * 3 + p][lane];

  // Per-lane gate epilogue. C-layout: col = lane&15 (unit),
  // row = batch = wm + mf*16 + (lane>>4)*4 + r  (verified in baseline).
  const int j  = g * 16 + (lane & 15);
  const int jb = (j >> 5) * ACHUNK + (j & 31);   // packed-A dest base
  const int qr = (lane >> 4) * 4;
  #pragma unroll
  for (int mf = 0; mf < 2; ++mf) {
    const int b0 = wm + mf * 16 + qr;
    floatx4 ho4 = *(const floatx4*)(hold + (size_t)j * B_ + b0);  // coalesced
    floatx4 hv4;
    #pragma unroll
    for (int r = 0; r < 4; ++r) {
      const int b = b0 + r;
      const size_t rx = ((size_t)b * S_ + t) * N3 + j;
      const float xr = (float)gx[rx];
      const float xi = (float)gx[rx + H_];
      const float xn = (float)gx[rx + 2 * H_];
      const float rg = 1.f / (1.f + __expf(-(xr + acc[mf][0][r])));
      const float ig = 1.f / (1.f + __expf(-(xi + acc[mf][1][r])));
      const float ta = xn + rg * acc[mf][2][r];
      const float nn = 1.f - 2.f / (1.f + __expf(2.f * ta));  // tanh(ta)
      const float hv = (1.f - ig) * nn + ig * ho4[r];
      hv4[r] = hv;
      Ap_new[jb + b * 32] = (half_t)hv;
      int lc = lengths[b] - 1;
      lc = lc < 0 ? 0 : (lc > S_ - 1 ? S_ - 1 : lc);
      if (t == lc) out[(size_t)b * H_ + j] = hv;
    }
    *(floatx4*)(hnew + (size_t)j * B_ + b0) = hv4;                // coalesced
  }
}

extern "C" void kernel_launch(void* const* d_in, const int* in_sizes, int n_in,
                              void* d_out, int out_size, void* d_ws, size_t ws_size,
                              hipStream_t stream)
{
  const int*   tokens  = (const int*)d_in[0];
  const int*   lengths = (const int*)d_in[1];
  const float* emb = (const float*)d_in[2];
  const float* Wir = (const float*)d_in[3];
  const float* Wii = (const float*)d_in[4];
  const float* Win = (const float*)d_in[5];
  const float* bir = (const float*)d_in[6];
  const float* bii = (const float*)d_in[7];
  const float* bin = (const float*)d_in[8];
  const float* Whr = (const float*)d_in[9];
  const float* Whi = (const float*)d_in[10];
  const float* Whn = (const float*)d_in[11];
  float* out = (float*)d_out;

  char* ws = (char*)d_ws;
  size_t off = 0;
  auto alloc = [&](size_t bytes) {
    void* p = ws + off;
    off = (off + bytes + 255) & ~(size_t)255;
    return p;
  };
  half_t* xb   = (half_t*)alloc((size_t)(B_ * S_) * EP * 2);   //  7.9 MB
  half_t* Wi   = (half_t*)alloc((size_t)N3 * EP * 2);          //  9.2 MB
  half_t* Wp   = (half_t*)alloc((size_t)GBLK * WBLK * 2);      // 34.6 MB packed
  float*  bias = (float*)alloc((size_t)N3 * 4);
  half_t* gx   = (half_t*)alloc((size_t)(B_ * S_) * N3 * 2);   // 88.5 MB
  float*  h0   = (float*)alloc((size_t)B_ * H_ * 4);           // ping-pong h [H][B]
  float*  h1   = (float*)alloc((size_t)B_ * H_ * 4);
  half_t* Ap0  = (half_t*)alloc((size_t)B_ * H_ * 2);          // packed hh
  half_t* Ap1  = (half_t*)alloc((size_t)B_ * H_ * 2);

  gather_cast_x<<<(B_ * S_ * EP) / 256, 256, 0, stream>>>(tokens, emb, xb);
  convert_wi<<<(N3 * EP) / 256, 256, 0, stream>>>(Wir, Wii, Win, bir, bii, bin, Wi, bias);
  for (int s = 0; s < WSLICES; ++s)
    convert_wh<<<(N3 * KH) / (256 * WSLICES), 256, 0, stream>>>(
        Whr, Whi, Whn, Wp, s * (N3 * KH / WSLICES));
  init_h<<<(B_ * H_) / 256, 256, 0, stream>>>(h0, Ap0);

  // Phase 1: gates_x, sliced 8x along M so gemm_gate owns the rocprof top-5.
  for (int s = 0; s < XSLICES; ++s)
    gemm_x<<<dim3(48 / XSLICES, 57), 256, 0, stream>>>(xb, Wi, gx, bias,
                                                       s * (48 / XSLICES));

  // Phase 2: 48 GRU steps, one block-local fused dispatch each (12 waves)
  for (int t = 0; t < S_; ++t) {
    const half_t* ai = (t & 1) ? Ap1 : Ap0;
    half_t*       aw = (t & 1) ? Ap0 : Ap1;
    const float*  ho = (t & 1) ? h1  : h0;
    float*        hn = (t & 1) ? h0  : h1;
    gemm_gate<<<dim3(GBLK), 768, 0, stream>>>(
        ai, Wp, gx, ho, hn, aw, lengths, out, t);
  }
}

// Round 9
// 1358.732 us; speedup vs baseline: 1.2749x; 1.2673x over previous
//
#include <hip/hip_runtime.h>
#include <stdint.h>
#include <stddef.h>

// Problem dims
#define B_  128
#define S_  48
#define E_  620
#define EP  640    // E padded to multiple of 32 (zeros)
#define H_  2400
#define N3  7200   // 3*H (r,i,n concatenated)
#define KH  2400
#define P1_ITERS 20  // phase-1 K = 640 = 20 x 32
#define KZ   5       // phase-2 cross-block K-split (480 k each)
#define KZI  15      // k-iters per block (480 / 32)
#define RING 5       // ring depth (15 % 5 == 0)
#define UG   48      // hidden units per group
#define NG   50      // unit groups (H_/UG)
// Packed geometry (halves)
#define WCHUNK 512           // one 16-unit x 32-k plane chunk = 1024 B
#define WITER  (9 * WCHUNK)  // halves per k-iter per (g,kz): 3 nw x 3 planes
#define ACHUNK (B_ * 32)     // halves per k-iter of packed A [kt][128][32]

typedef _Float16 half_t;
typedef __attribute__((ext_vector_type(8))) _Float16 half8;
typedef __attribute__((ext_vector_type(4))) _Float16 half4;
typedef __attribute__((ext_vector_type(4))) float    floatx4;

// Workgroup barrier that waits ONLY on LDS ops; in-flight global loads keep
// flying. 0xC07F = vmcnt(63) expcnt(7) lgkmcnt(0).  (phase-1 only)
__device__ __forceinline__ void lds_barrier() {
  __builtin_amdgcn_sched_barrier(0);
  __builtin_amdgcn_s_waitcnt(0xC07F);
  __builtin_amdgcn_s_barrier();
  __builtin_amdgcn_sched_barrier(0);
}

// ---- x = fp16(emb[tokens]), padded [6144, 640] ----
__global__ void gather_cast_x(const int* __restrict__ tokens,
                              const float* __restrict__ emb,
                              half_t* __restrict__ xb) {
  int idx = blockIdx.x * 256 + threadIdx.x;       // over 6144*EP
  int m = idx / EP, c = idx - m * EP;
  float v = 0.f;
  if (c < E_) v = emb[(size_t)tokens[m] * E_ + c];
  xb[idx] = (half_t)v;
}

// ---- W_i = fp16 concat(W_ir,W_ii,W_in) [7200, 640]; bias concat [7200] ----
__global__ void convert_wi(const float* __restrict__ Wir, const float* __restrict__ Wii,
                           const float* __restrict__ Win,
                           const float* __restrict__ bir, const float* __restrict__ bii,
                           const float* __restrict__ bin,
                           half_t* __restrict__ Wi, float* __restrict__ bias) {
  int idx = blockIdx.x * 256 + threadIdx.x;       // over N3*EP
  int r = idx / EP, c = idx - r * EP;
  const float* W = (r < H_) ? Wir : (r < 2*H_ ? Wii : Win);
  int rr = (r < H_) ? r : (r < 2*H_ ? r - H_ : r - 2*H_);
  float v = (c < E_) ? W[(size_t)rr * E_ + c] : 0.f;
  Wi[idx] = (half_t)v;
  if (c == 0) {
    const float* bb = (r < H_) ? bir : (r < 2*H_ ? bii : bin);
    bias[r] = bb[rr];
  }
}

// ---- Wp = fp16 PACKED recurrent weights ----
// Layout: Wp[g50][kz5][kt15][chunk9 = nw*3+plane][fm16][k32]; each chunk is
// 1024 B = exactly one wave's contiguous MFMA B-frag load.
__global__ void convert_wh(const float* __restrict__ Whr, const float* __restrict__ Whi,
                           const float* __restrict__ Whn, half_t* __restrict__ Wp) {
  int idx = blockIdx.x * 256 + threadIdx.x;       // over N3*KH
  int r3 = idx / KH, c = idx - r3 * KH;
  const float* W = (r3 < H_) ? Whr : (r3 < 2*H_ ? Whi : Whn);
  int p  = (r3 < H_) ? 0 : (r3 < 2*H_ ? 1 : 2);
  int rr = r3 - p * H_;
  int g = rr / UG, u = rr - g * UG;
  int nw = u >> 4, fm = u & 15;
  int kz = c / 480, kt = (c - kz * 480) >> 5, ksub = c & 31;
  size_t dst = ((((size_t)(g * KZ + kz) * KZI + kt) * 9 + (nw * 3 + p)) * 16 + fm) * 32
               + ksub;
  Wp[dst] = (half_t)W[(size_t)rr * KH + c];
}

__global__ void init_h(float* __restrict__ h, half_t* __restrict__ Ap) {
  int idx = blockIdx.x * 256 + threadIdx.x;       // over B_*H_
  h[idx] = 0.f;
  Ap[idx] = (half_t)0.f;
}

// ---- Phase 1: gx = fp16( xb @ Wi^T + bias )  [6144 x 7200], K=640 ----
// (r5/r6 structure: 128x128 tile, frag-major LDS dbuf, lgkm-only barrier.)
__global__ __launch_bounds__(256, 2) void gemm_x(
    const half_t* __restrict__ A,   // xb [6144 x 640]
    const half_t* __restrict__ Bm,  // Wi [7200 x 640]
    half_t* __restrict__ C,         // gx [6144 x 7200]
    const float* __restrict__ bias)
{
  __shared__ half_t As[2][4096];
  __shared__ half_t Bs[2][4096];

  const int tid = threadIdx.x;
  const int lane = tid & 63;
  const int w = tid >> 6;
  const int m0 = blockIdx.x * 128;
  const int n0 = blockIdx.y * 128;
  const int wm = (w >> 1) * 64, wn = (w & 1) * 64;

  const int c0 = tid, c1 = tid + 256;
  const int rA0 = m0 + (c0 >> 6) * 16 + (c0 & 15), q0 = ((c0 >> 4) & 3) * 8;
  const int rA1 = m0 + (c1 >> 6) * 16 + (c1 & 15), q1 = ((c1 >> 4) & 3) * 8;
  int rB0 = n0 + (c0 >> 6) * 16 + (c0 & 15); if (rB0 >= N3) rB0 = N3 - 1;
  int rB1 = n0 + (c1 >> 6) * 16 + (c1 & 15); if (rB1 >= N3) rB1 = N3 - 1;
  const half_t* pA0 = A  + (size_t)rA0 * EP + q0;
  const half_t* pA1 = A  + (size_t)rA1 * EP + q1;
  const half_t* pB0 = Bm + (size_t)rB0 * EP + q0;
  const half_t* pB1 = Bm + (size_t)rB1 * EP + q1;

  floatx4 acc[4][4] = {};

  half8 ga0 = *(const half8*)(pA0);
  half8 ga1 = *(const half8*)(pA1);
  half8 gb0 = *(const half8*)(pB0);
  half8 gb1 = *(const half8*)(pB1);
  *(half8*)(As[0] + c0 * 8) = ga0;
  *(half8*)(As[0] + c1 * 8) = ga1;
  *(half8*)(Bs[0] + c0 * 8) = gb0;
  *(half8*)(Bs[0] + c1 * 8) = gb1;
  ga0 = *(const half8*)(pA0 + 32);
  ga1 = *(const half8*)(pA1 + 32);
  gb0 = *(const half8*)(pB0 + 32);
  gb1 = *(const half8*)(pB1 + 32);
  lds_barrier();

  #pragma unroll
  for (int i = 0; i < P1_ITERS; ++i) {
    const int cur = i & 1, nxt = cur ^ 1;
    half8 a[4], b[4];
    #pragma unroll
    for (int f = 0; f < 4; ++f) {
      a[f] = *(const half8*)(As[cur] + (((wm >> 4) + f) * 64 + lane) * 8);
      b[f] = *(const half8*)(Bs[cur] + (((wn >> 4) + f) * 64 + lane) * 8);
    }
    if (i + 1 < P1_ITERS) {
      *(half8*)(As[nxt] + c0 * 8) = ga0;
      *(half8*)(As[nxt] + c1 * 8) = ga1;
      *(half8*)(Bs[nxt] + c0 * 8) = gb0;
      *(half8*)(Bs[nxt] + c1 * 8) = gb1;
    }
    if (i + 2 < P1_ITERS) {
      int ko = (i + 2) * 32;
      ga0 = *(const half8*)(pA0 + ko);
      ga1 = *(const half8*)(pA1 + ko);
      gb0 = *(const half8*)(pB0 + ko);
      gb1 = *(const half8*)(pB1 + ko);
    }
    #pragma unroll
    for (int mf = 0; mf < 4; ++mf)
      #pragma unroll
      for (int nf = 0; nf < 4; ++nf)
        acc[mf][nf] = __builtin_amdgcn_mfma_f32_16x16x32_f16(
            a[mf], b[nf], acc[mf][nf], 0, 0, 0);
    if (i + 1 < P1_ITERS) lds_barrier();
  }

  const int col = lane & 15, qr = (lane >> 4) * 4;
  #pragma unroll
  for (int nf = 0; nf < 4; ++nf) {
    int n = n0 + wn + nf * 16 + col;
    if (n >= N3) continue;
    float bv = bias[n];
    #pragma unroll
    for (int mf = 0; mf < 4; ++mf)
      #pragma unroll
      for (int r = 0; r < 4; ++r)
        C[(size_t)(m0 + wm + mf * 16 + qr + r) * N3 + n] =
            (half_t)(acc[mf][nf][r] + bv);
  }
}

// ---- Phase 2a: recurrent GEMM partials, grid (50 g, 5 kz, 3 nw) x 256. ----
// Byte-diet redesign: 48 units/group cuts the full-state A re-read from
// 150x614KB=92MB to 50x614KB=31MB/step; kz=5 cross-block K-split restores
// parallelism (750 blocks ~ 2.9/CU over all 256 CUs) at zero A-traffic cost;
// partials stored fp16 (halves the Gp round-trip; |err|~1e-3 << 0.02 thr).
// Block = 4 mw waves (32 batch rows each), each fully independent: no LDS,
// no barriers, no atomics. All fragment loads are contiguous 1024 B (packed
// Wp/Ap layouts). Per wave-iter: 5 x 1KB loads, 6 MFMA; rings depth 5.
__global__ __launch_bounds__(256, 3) void gru_gemm(
    const half_t* __restrict__ Ap_old,  // packed hh [75 kt][128][32]
    const half_t* __restrict__ Wp,      // packed [50][5][15][9][512]
    half_t* __restrict__ Gp)            // partials [5 kz][128 b][3 p][2400 j]
{
  const int tid  = threadIdx.x;
  const int lane = tid & 63;
  const int mw   = tid >> 6;        // 0..3 batch stripe
  const int g    = blockIdx.x;      // 0..49
  const int kz   = blockIdx.y;      // 0..4
  const int nw   = blockIdx.z;      // 0..2 unit-16 sub-group
  const int wm   = mw * 32;

  const int fm = lane & 15;
  const int fk = (lane >> 4) * 8;

  const half_t* pA = Ap_old + (size_t)kz * KZI * ACHUNK + (wm + fm) * 32 + fk;
  const half_t* pB = Wp + ((size_t)(g * KZ + kz) * KZI * 9 + nw * 3) * WCHUNK
                        + fm * 32 + fk;

  floatx4 acc[2][3] = {};   // [mf][plane]

  half8 aR[RING][2];
  half8 bR[RING][3];
  #pragma unroll
  for (int d = 0; d < RING; ++d) {
    aR[d][0] = *(const half8*)(pA + d * ACHUNK);
    aR[d][1] = *(const half8*)(pA + d * ACHUNK + 512);
    bR[d][0] = *(const half8*)(pB + d * WITER);
    bR[d][1] = *(const half8*)(pB + d * WITER + WCHUNK);
    bR[d][2] = *(const half8*)(pB + d * WITER + 2 * WCHUNK);
  }

  #pragma unroll
  for (int i = 0; i < KZI; ++i) {
    const int s = i % RING;
    half8 a0 = aR[s][0], a1 = aR[s][1];
    half8 br = bR[s][0], bi = bR[s][1], bn = bR[s][2];
    if (i + RING < KZI) {
      aR[s][0] = *(const half8*)(pA + (i + RING) * ACHUNK);
      aR[s][1] = *(const half8*)(pA + (i + RING) * ACHUNK + 512);
      bR[s][0] = *(const half8*)(pB + (i + RING) * WITER);
      bR[s][1] = *(const half8*)(pB + (i + RING) * WITER + WCHUNK);
      bR[s][2] = *(const half8*)(pB + (i + RING) * WITER + 2 * WCHUNK);
    }
    acc[0][0] = __builtin_amdgcn_mfma_f32_16x16x32_f16(a0, br, acc[0][0], 0, 0, 0);
    acc[1][0] = __builtin_amdgcn_mfma_f32_16x16x32_f16(a1, br, acc[1][0], 0, 0, 0);
    acc[0][1] = __builtin_amdgcn_mfma_f32_16x16x32_f16(a0, bi, acc[0][1], 0, 0, 0);
    acc[1][1] = __builtin_amdgcn_mfma_f32_16x16x32_f16(a1, bi, acc[1][1], 0, 0, 0);
    acc[0][2] = __builtin_amdgcn_mfma_f32_16x16x32_f16(a0, bn, acc[0][2], 0, 0, 0);
    acc[1][2] = __builtin_amdgcn_mfma_f32_16x16x32_f16(a1, bn, acc[1][2], 0, 0, 0);
  }

  // fp16 partial store. C-layout: col = lane&15 (unit), row = batch.
  const int j  = g * UG + nw * 16 + (lane & 15);
  const int qr = (lane >> 4) * 4;
  #pragma unroll
  for (int mf = 0; mf < 2; ++mf)
    #pragma unroll
    for (int p = 0; p < 3; ++p)
      #pragma unroll
      for (int r = 0; r < 4; ++r) {
        const int b = wm + mf * 16 + qr + r;
        Gp[((size_t)(kz * B_ + b) * 3 + p) * H_ + j] = (half_t)acc[mf][p][r];
      }
}

// ---- Phase 2b: gate update. grid 300 x 256; thread = (b, 4 units). ----
// Fully coalesced: 15 half4 partial loads + 3 half4 gx + 1 floatx4 h.
__global__ void gru_gate(
    const half_t* __restrict__ Gp,      // [5][128][3][2400]
    const half_t* __restrict__ gx,      // [6144 x 7200]
    const float* __restrict__ hold,     // [B][H] fp32
    float* __restrict__ hnew,
    half_t* __restrict__ Ap_new,        // packed hh [75][128][32]
    const int* __restrict__ lengths,
    float* __restrict__ out,            // [B][H]
    int t)
{
  const int idx = blockIdx.x * 256 + threadIdx.x;   // over 128 * 600
  const int b = idx / 600;
  const int j = (idx - b * 600) * 4;

  floatx4 G[3] = {};
  #pragma unroll
  for (int kz = 0; kz < KZ; ++kz)
    #pragma unroll
    for (int p = 0; p < 3; ++p) {
      half4 v = *(const half4*)(Gp + ((size_t)(kz * B_ + b) * 3 + p) * H_ + j);
      #pragma unroll
      for (int e = 0; e < 4; ++e) G[p][e] += (float)v[e];
    }

  const size_t rx = ((size_t)b * S_ + t) * N3 + j;
  half4 hxr = *(const half4*)(gx + rx);
  half4 hxi = *(const half4*)(gx + rx + H_);
  half4 hxn = *(const half4*)(gx + rx + 2 * H_);
  floatx4 ho = *(const floatx4*)(hold + (size_t)b * H_ + j);

  floatx4 hv4;
  half4 ap4;
  #pragma unroll
  for (int e = 0; e < 4; ++e) {
    const float rg = 1.f / (1.f + __expf(-((float)hxr[e] + G[0][e])));
    const float ig = 1.f / (1.f + __expf(-((float)hxi[e] + G[1][e])));
    const float ta = (float)hxn[e] + rg * G[2][e];
    const float nn = 1.f - 2.f / (1.f + __expf(2.f * ta));  // tanh(ta)
    hv4[e] = (1.f - ig) * nn + ig * ho[e];
    ap4[e] = (half_t)hv4[e];
  }
  *(floatx4*)(hnew + (size_t)b * H_ + j) = hv4;
  *(half4*)(Ap_new + (size_t)(j >> 5) * ACHUNK + b * 32 + (j & 31)) = ap4;

  int lc = lengths[b] - 1;
  lc = lc < 0 ? 0 : (lc > S_ - 1 ? S_ - 1 : lc);
  if (t == lc) *(floatx4*)(out + (size_t)b * H_ + j) = hv4;
}

extern "C" void kernel_launch(void* const* d_in, const int* in_sizes, int n_in,
                              void* d_out, int out_size, void* d_ws, size_t ws_size,
                              hipStream_t stream)
{
  const int*   tokens  = (const int*)d_in[0];
  const int*   lengths = (const int*)d_in[1];
  const float* emb = (const float*)d_in[2];
  const float* Wir = (const float*)d_in[3];
  const float* Wii = (const float*)d_in[4];
  const float* Win = (const float*)d_in[5];
  const float* bir = (const float*)d_in[6];
  const float* bii = (const float*)d_in[7];
  const float* bin = (const float*)d_in[8];
  const float* Whr = (const float*)d_in[9];
  const float* Whi = (const float*)d_in[10];
  const float* Whn = (const float*)d_in[11];
  float* out = (float*)d_out;

  char* ws = (char*)d_ws;
  size_t off = 0;
  auto alloc = [&](size_t bytes) {
    void* p = ws + off;
    off = (off + bytes + 255) & ~(size_t)255;
    return p;
  };
  half_t* xb   = (half_t*)alloc((size_t)(B_ * S_) * EP * 2);   //  7.9 MB
  half_t* Wi   = (half_t*)alloc((size_t)N3 * EP * 2);          //  9.2 MB
  half_t* Wp   = (half_t*)alloc((size_t)N3 * KH * 2);          // 34.6 MB packed
  float*  bias = (float*)alloc((size_t)N3 * 4);
  half_t* gx   = (half_t*)alloc((size_t)(B_ * S_) * N3 * 2);   // 88.5 MB
  half_t* Gp   = (half_t*)alloc((size_t)KZ * B_ * N3 * 2);     //  9.2 MB fp16
  float*  h0   = (float*)alloc((size_t)B_ * H_ * 4);           // ping-pong h [B][H]
  float*  h1   = (float*)alloc((size_t)B_ * H_ * 4);
  half_t* Ap0  = (half_t*)alloc((size_t)B_ * H_ * 2);          // packed hh
  half_t* Ap1  = (half_t*)alloc((size_t)B_ * H_ * 2);

  gather_cast_x<<<(B_ * S_ * EP) / 256, 256, 0, stream>>>(tokens, emb, xb);
  convert_wi<<<(N3 * EP) / 256, 256, 0, stream>>>(Wir, Wii, Win, bir, bii, bin, Wi, bias);
  convert_wh<<<(N3 * KH) / 256, 256, 0, stream>>>(Whr, Whi, Whn, Wp);
  init_h<<<(B_ * H_) / 256, 256, 0, stream>>>(h0, Ap0);

  // Phase 1: gates_x = fp16( x @ W_i^T + b )   [6144 x 7200]
  gemm_x<<<dim3(48, 57), 256, 0, stream>>>(xb, Wi, gx, bias);

  // Phase 2: 48 GRU steps x {750-block partial GEMM, 300-block gate update}
  for (int t = 0; t < S_; ++t) {
    const half_t* ai = (t & 1) ? Ap1 : Ap0;
    half_t*       aw = (t & 1) ? Ap0 : Ap1;
    const float*  ho = (t & 1) ? h1  : h0;
    float*        hn = (t & 1) ? h0  : h1;
    gru_gemm<<<dim3(NG, KZ, 3), 256, 0, stream>>>(ai, Wp, Gp);
    gru_gate<<<(B_ * H_ / 4) / 256, 256, 0, stream>>>(
        Gp, gx, ho, hn, aw, lengths, out, t);
  }
}

// Round 10
// 1036.295 us; speedup vs baseline: 1.6716x; 1.3111x over previous
//
#include <hip/hip_runtime.h>
#include <stdint.h>
#include <stddef.h>

// Problem dims
#define B_  128
#define S_  48
#define E_  620
#define EP  640    // E padded to multiple of 32 (zeros)
#define H_  2400
#define N3  7200   // 3*H (r,i,n concatenated)
#define KH  2400
#define P1_ITERS 20  // phase-1 K = 640 = 20 x 32
#define KZ   5       // phase-2 cross-block K-split (480 k each)
#define KZI  15      // k-iters per block (480 / 32)
#define UG   48      // hidden units per group (3 nw x 16)
#define NG   50      // unit groups (H_/UG)
// Lane-major packed geometry (halves):
//   one 16-row x 32-k chunk = 512 halves laid out [lane64][8]: the half that
//   MFMA lane l consumes at k-slot e sits at l*8+e. LDS staging is then an
//   identity copy and every fragment read (global or LDS) is a contiguous
//   1024-B wave access.
#define WCHUNK 512            // one plane chunk
#define WIT    (9 * WCHUNK)   // W halves per k-iter per (g,kz): 3 nw x 3 planes
#define ACH    4096           // A halves per k-iter: [mw4][mf2][lane64][8]

typedef _Float16 half_t;
typedef __attribute__((ext_vector_type(8))) _Float16 half8;
typedef __attribute__((ext_vector_type(4))) _Float16 half4;
typedef __attribute__((ext_vector_type(4))) float    floatx4;

// Workgroup barrier that waits ONLY on LDS ops; in-flight global loads keep
// flying. 0xC07F = vmcnt(63) expcnt(7) lgkmcnt(0).
__device__ __forceinline__ void lds_barrier() {
  __builtin_amdgcn_sched_barrier(0);
  __builtin_amdgcn_s_waitcnt(0xC07F);
  __builtin_amdgcn_s_barrier();
  __builtin_amdgcn_sched_barrier(0);
}

// ---- x = fp16(emb[tokens]), padded [6144, 640] ----
__global__ void gather_cast_x(const int* __restrict__ tokens,
                              const float* __restrict__ emb,
                              half_t* __restrict__ xb) {
  int idx = blockIdx.x * 256 + threadIdx.x;       // over 6144*EP
  int m = idx / EP, c = idx - m * EP;
  float v = 0.f;
  if (c < E_) v = emb[(size_t)tokens[m] * E_ + c];
  xb[idx] = (half_t)v;
}

// ---- W_i = fp16 concat(W_ir,W_ii,W_in) [7200, 640]; bias concat [7200] ----
__global__ void convert_wi(const float* __restrict__ Wir, const float* __restrict__ Wii,
                           const float* __restrict__ Win,
                           const float* __restrict__ bir, const float* __restrict__ bii,
                           const float* __restrict__ bin,
                           half_t* __restrict__ Wi, float* __restrict__ bias) {
  int idx = blockIdx.x * 256 + threadIdx.x;       // over N3*EP
  int r = idx / EP, c = idx - r * EP;
  const float* W = (r < H_) ? Wir : (r < 2*H_ ? Wii : Win);
  int rr = (r < H_) ? r : (r < 2*H_ ? r - H_ : r - 2*H_);
  float v = (c < E_) ? W[(size_t)rr * E_ + c] : 0.f;
  Wi[idx] = (half_t)v;
  if (c == 0) {
    const float* bb = (r < H_) ? bir : (r < 2*H_ ? bii : bin);
    bias[r] = bb[rr];
  }
}

// ---- Wp = fp16 PACKED recurrent weights, lane-major chunks ----
// Wp[g50][kz5][kt15][chunk9 = nw*3+plane][lane64][e8]
__global__ void convert_wh(const float* __restrict__ Whr, const float* __restrict__ Whi,
                           const float* __restrict__ Whn, half_t* __restrict__ Wp) {
  int idx = blockIdx.x * 256 + threadIdx.x;       // over N3*KH
  int r3 = idx / KH, c = idx - r3 * KH;
  const float* W = (r3 < H_) ? Whr : (r3 < 2*H_ ? Whi : Whn);
  int p  = (r3 < H_) ? 0 : (r3 < 2*H_ ? 1 : 2);
  int rr = r3 - p * H_;
  int g = rr / UG, u = rr - g * UG;
  int nw = u >> 4, fm = u & 15;
  int kz = c / 480, kt = (c - kz * 480) >> 5, ksub = c & 31;
  size_t chunk = ((size_t)(g * KZ + kz) * KZI + kt) * 9 + (nw * 3 + p);
  size_t dst = chunk * WCHUNK + ((ksub >> 3) * 16 + fm) * 8 + (ksub & 7);
  Wp[dst] = (half_t)W[(size_t)rr * KH + c];
}

__global__ void init_h(float* __restrict__ h, half_t* __restrict__ Ap) {
  int idx = blockIdx.x * 256 + threadIdx.x;       // over B_*H_
  h[idx] = 0.f;
  Ap[idx] = (half_t)0.f;
}

// ---- Phase 1: gx = fp16( xb @ Wi^T + bias )  [6144 x 7200], K=640 ----
__global__ __launch_bounds__(256, 2) void gemm_x(
    const half_t* __restrict__ A,   // xb [6144 x 640]
    const half_t* __restrict__ Bm,  // Wi [7200 x 640]
    half_t* __restrict__ C,         // gx [6144 x 7200]
    const float* __restrict__ bias)
{
  __shared__ half_t As[2][4096];
  __shared__ half_t Bs[2][4096];

  const int tid = threadIdx.x;
  const int lane = tid & 63;
  const int w = tid >> 6;
  const int m0 = blockIdx.x * 128;
  const int n0 = blockIdx.y * 128;
  const int wm = (w >> 1) * 64, wn = (w & 1) * 64;

  const int c0 = tid, c1 = tid + 256;
  const int rA0 = m0 + (c0 >> 6) * 16 + (c0 & 15), q0 = ((c0 >> 4) & 3) * 8;
  const int rA1 = m0 + (c1 >> 6) * 16 + (c1 & 15), q1 = ((c1 >> 4) & 3) * 8;
  int rB0 = n0 + (c0 >> 6) * 16 + (c0 & 15); if (rB0 >= N3) rB0 = N3 - 1;
  int rB1 = n0 + (c1 >> 6) * 16 + (c1 & 15); if (rB1 >= N3) rB1 = N3 - 1;
  const half_t* pA0 = A  + (size_t)rA0 * EP + q0;
  const half_t* pA1 = A  + (size_t)rA1 * EP + q1;
  const half_t* pB0 = Bm + (size_t)rB0 * EP + q0;
  const half_t* pB1 = Bm + (size_t)rB1 * EP + q1;

  floatx4 acc[4][4] = {};

  half8 ga0 = *(const half8*)(pA0);
  half8 ga1 = *(const half8*)(pA1);
  half8 gb0 = *(const half8*)(pB0);
  half8 gb1 = *(const half8*)(pB1);
  *(half8*)(As[0] + c0 * 8) = ga0;
  *(half8*)(As[0] + c1 * 8) = ga1;
  *(half8*)(Bs[0] + c0 * 8) = gb0;
  *(half8*)(Bs[0] + c1 * 8) = gb1;
  ga0 = *(const half8*)(pA0 + 32);
  ga1 = *(const half8*)(pA1 + 32);
  gb0 = *(const half8*)(pB0 + 32);
  gb1 = *(const half8*)(pB1 + 32);
  lds_barrier();

  #pragma unroll
  for (int i = 0; i < P1_ITERS; ++i) {
    const int cur = i & 1, nxt = cur ^ 1;
    half8 a[4], b[4];
    #pragma unroll
    for (int f = 0; f < 4; ++f) {
      a[f] = *(const half8*)(As[cur] + (((wm >> 4) + f) * 64 + lane) * 8);
      b[f] = *(const half8*)(Bs[cur] + (((wn >> 4) + f) * 64 + lane) * 8);
    }
    if (i + 1 < P1_ITERS) {
      *(half8*)(As[nxt] + c0 * 8) = ga0;
      *(half8*)(As[nxt] + c1 * 8) = ga1;
      *(half8*)(Bs[nxt] + c0 * 8) = gb0;
      *(half8*)(Bs[nxt] + c1 * 8) = gb1;
    }
    if (i + 2 < P1_ITERS) {
      int ko = (i + 2) * 32;
      ga0 = *(const half8*)(pA0 + ko);
      ga1 = *(const half8*)(pA1 + ko);
      gb0 = *(const half8*)(pB0 + ko);
      gb1 = *(const half8*)(pB1 + ko);
    }
    #pragma unroll
    for (int mf = 0; mf < 4; ++mf)
      #pragma unroll
      for (int nf = 0; nf < 4; ++nf)
        acc[mf][nf] = __builtin_amdgcn_mfma_f32_16x16x32_f16(
            a[mf], b[nf], acc[mf][nf], 0, 0, 0);
    if (i + 1 < P1_ITERS) lds_barrier();
  }

  const int col = lane & 15, qr = (lane >> 4) * 4;
  #pragma unroll
  for (int nf = 0; nf < 4; ++nf) {
    int n = n0 + wn + nf * 16 + col;
    if (n >= N3) continue;
    float bv = bias[n];
    #pragma unroll
    for (int mf = 0; mf < 4; ++mf)
      #pragma unroll
      for (int r = 0; r < 4; ++r)
        C[(size_t)(m0 + wm + mf * 16 + qr + r) * N3 + n] =
            (half_t)(acc[mf][nf][r] + bv);
  }
}

// ---- Phase 2a: recurrent GEMM partials, grid (50 g, 5 kz) x 768 thr. ----
// LDS-staged dedup: the block stages A (8 KB) + W (9 KB) per k-iter ONCE
// into double-buffered LDS (identity copy: lane-major global layouts are
// contiguous streams); 12 waves = 3 nw x 4 mw consume fragments as
// contiguous 1024-B ds_read_b128. Issued global bytes drop from ~880 KB to
// ~255 KB per CU per step (the L1/TA port was the wall); fragment traffic
// moves to the LDS pipe (~60 KB/iter, ~3 us/step floor). Barrier pattern =
// gemm_x's proven reg-carry dbuf with lgkm-only lds_barrier.
__global__ __launch_bounds__(768, 3) void gru_gemm(
    const half_t* __restrict__ Ap_old,  // [75 kt][4 mw][2 mf][512] lane-major
    const half_t* __restrict__ Wp,      // [50][5][15][9][512] lane-major
    half_t* __restrict__ Gp)            // partials [5 kz][128 b][3 p][2400 j]
{
  __shared__ half_t S[2][8704];   // per buf: A halves 0..4095, W 4096..8703

  const int tid  = threadIdx.x;
  const int lane = tid & 63;
  const int w    = tid >> 6;        // 0..11
  const int mw   = w & 3;           // batch stripe (32 rows)
  const int nw   = w >> 2;          // unit-16 sub-group (0..2)
  const int g    = blockIdx.x;      // 0..49
  const int kz   = blockIdx.y;      // 0..4

  const half_t* Asrc = Ap_old + (size_t)kz * KZI * ACH;
  const half_t* Wsrc = Wp + (size_t)(g * KZ + kz) * KZI * WIT;

  // Staging plan per k-iter (1088 x 16-B units): threads 0..511 -> A unit
  // tid; threads 512..767 -> W unit tid-512; threads 0..319 additionally ->
  // W unit tid+256. All branches are wave-uniform (512 = 8 waves, 320 = 5).
  const bool isA  = tid < 512;
  const bool has1 = tid < 320;
  const half_t* sb0 = isA ? (Asrc + tid * 8) : (Wsrc + (tid - 512) * 8);
  const int     st0 = isA ? ACH : WIT;
  const half_t* sb1 = Wsrc + (tid + 256) * 8;
  const int d0 = tid * 8;                   // A region (t<512) / W region
  const int d1 = ACH + (tid + 256) * 8;

  half8 r0 = *(const half8*)(sb0);
  half8 r1{};
  if (has1) r1 = *(const half8*)(sb1);
  *(half8*)(&S[0][d0]) = r0;
  if (has1) *(half8*)(&S[0][d1]) = r1;
  r0 = *(const half8*)(sb0 + st0);
  if (has1) r1 = *(const half8*)(sb1 + WIT);
  lds_barrier();

  floatx4 acc[2][3] = {};   // [mf][plane]
  const int aoff0 = (mw * 2 + 0) * 512 + lane * 8;
  const int aoff1 = (mw * 2 + 1) * 512 + lane * 8;
  const int woff  = ACH + nw * 3 * 512 + lane * 8;

  #pragma unroll
  for (int i = 0; i < KZI; ++i) {
    const int cur = i & 1, nxt = cur ^ 1;
    half8 a0 = *(const half8*)(&S[cur][aoff0]);
    half8 a1 = *(const half8*)(&S[cur][aoff1]);
    half8 b0 = *(const half8*)(&S[cur][woff]);
    half8 b1 = *(const half8*)(&S[cur][woff + 512]);
    half8 b2 = *(const half8*)(&S[cur][woff + 1024]);
    if (i + 1 < KZI) {
      *(half8*)(&S[nxt][d0]) = r0;
      if (has1) *(half8*)(&S[nxt][d1]) = r1;
    }
    if (i + 2 < KZI) {
      r0 = *(const half8*)(sb0 + (size_t)(i + 2) * st0);
      if (has1) r1 = *(const half8*)(sb1 + (size_t)(i + 2) * WIT);
    }
    acc[0][0] = __builtin_amdgcn_mfma_f32_16x16x32_f16(a0, b0, acc[0][0], 0, 0, 0);
    acc[1][0] = __builtin_amdgcn_mfma_f32_16x16x32_f16(a1, b0, acc[1][0], 0, 0, 0);
    acc[0][1] = __builtin_amdgcn_mfma_f32_16x16x32_f16(a0, b1, acc[0][1], 0, 0, 0);
    acc[1][1] = __builtin_amdgcn_mfma_f32_16x16x32_f16(a1, b1, acc[1][1], 0, 0, 0);
    acc[0][2] = __builtin_amdgcn_mfma_f32_16x16x32_f16(a0, b2, acc[0][2], 0, 0, 0);
    acc[1][2] = __builtin_amdgcn_mfma_f32_16x16x32_f16(a1, b2, acc[1][2], 0, 0, 0);
    if (i + 1 < KZI) lds_barrier();
  }

  // fp16 partial store. C-layout: col = lane&15 (unit), row = batch.
  const int j  = g * UG + nw * 16 + (lane & 15);
  const int wm = mw * 32;
  const int qr = (lane >> 4) * 4;
  #pragma unroll
  for (int mf = 0; mf < 2; ++mf)
    #pragma unroll
    for (int p = 0; p < 3; ++p)
      #pragma unroll
      for (int r = 0; r < 4; ++r) {
        const int b = wm + mf * 16 + qr + r;
        Gp[((size_t)(kz * B_ + b) * 3 + p) * H_ + j] = (half_t)acc[mf][p][r];
      }
}

// ---- Phase 2b: gate update. grid 300 x 256; thread = (b, 4 units). ----
__global__ void gru_gate(
    const half_t* __restrict__ Gp,      // [5][128][3][2400]
    const half_t* __restrict__ gx,      // [6144 x 7200]
    const float* __restrict__ hold,     // [B][H] fp32
    float* __restrict__ hnew,
    half_t* __restrict__ Ap_new,        // packed hh, lane-major
    const int* __restrict__ lengths,
    float* __restrict__ out,            // [B][H]
    int t)
{
  const int idx = blockIdx.x * 256 + threadIdx.x;   // over 128 * 600
  const int b = idx / 600;
  const int j = (idx - b * 600) * 4;

  floatx4 G[3] = {};
  #pragma unroll
  for (int kz = 0; kz < KZ; ++kz)
    #pragma unroll
    for (int p = 0; p < 3; ++p) {
      half4 v = *(const half4*)(Gp + ((size_t)(kz * B_ + b) * 3 + p) * H_ + j);
      #pragma unroll
      for (int e = 0; e < 4; ++e) G[p][e] += (float)v[e];
    }

  const size_t rx = ((size_t)b * S_ + t) * N3 + j;
  half4 hxr = *(const half4*)(gx + rx);
  half4 hxi = *(const half4*)(gx + rx + H_);
  half4 hxn = *(const half4*)(gx + rx + 2 * H_);
  floatx4 ho = *(const floatx4*)(hold + (size_t)b * H_ + j);

  floatx4 hv4;
  half4 ap4;
  #pragma unroll
  for (int e = 0; e < 4; ++e) {
    const float rg = 1.f / (1.f + __expf(-((float)hxr[e] + G[0][e])));
    const float ig = 1.f / (1.f + __expf(-((float)hxi[e] + G[1][e])));
    const float ta = (float)hxn[e] + rg * G[2][e];
    const float nn = 1.f - 2.f / (1.f + __expf(2.f * ta));  // tanh(ta)
    hv4[e] = (1.f - ig) * nn + ig * ho[e];
    ap4[e] = (half_t)hv4[e];
  }
  *(floatx4*)(hnew + (size_t)b * H_ + j) = hv4;

  // lane-major packed-A store: kt = j>>5; within chunk [mw][mf][lane][8]
  const int kt = j >> 5, ksub = j & 31;
  const int mwb = b >> 5, rb = b & 31, mfb = rb >> 4, fmb = rb & 15;
  const size_t pos = (size_t)kt * ACH + (mwb * 2 + mfb) * 512
                   + ((ksub >> 3) * 16 + fmb) * 8 + (ksub & 7);
  *(half4*)(Ap_new + pos) = ap4;

  int lc = lengths[b] - 1;
  lc = lc < 0 ? 0 : (lc > S_ - 1 ? S_ - 1 : lc);
  if (t == lc) *(floatx4*)(out + (size_t)b * H_ + j) = hv4;
}

extern "C" void kernel_launch(void* const* d_in, const int* in_sizes, int n_in,
                              void* d_out, int out_size, void* d_ws, size_t ws_size,
                              hipStream_t stream)
{
  const int*   tokens  = (const int*)d_in[0];
  const int*   lengths = (const int*)d_in[1];
  const float* emb = (const float*)d_in[2];
  const float* Wir = (const float*)d_in[3];
  const float* Wii = (const float*)d_in[4];
  const float* Win = (const float*)d_in[5];
  const float* bir = (const float*)d_in[6];
  const float* bii = (const float*)d_in[7];
  const float* bin = (const float*)d_in[8];
  const float* Whr = (const float*)d_in[9];
  const float* Whi = (const float*)d_in[10];
  const float* Whn = (const float*)d_in[11];
  float* out = (float*)d_out;

  char* ws = (char*)d_ws;
  size_t off = 0;
  auto alloc = [&](size_t bytes) {
    void* p = ws + off;
    off = (off + bytes + 255) & ~(size_t)255;
    return p;
  };
  half_t* xb   = (half_t*)alloc((size_t)(B_ * S_) * EP * 2);   //  7.9 MB
  half_t* Wi   = (half_t*)alloc((size_t)N3 * EP * 2);          //  9.2 MB
  half_t* Wp   = (half_t*)alloc((size_t)N3 * KH * 2);          // 34.6 MB packed
  float*  bias = (float*)alloc((size_t)N3 * 4);
  half_t* gx   = (half_t*)alloc((size_t)(B_ * S_) * N3 * 2);   // 88.5 MB
  half_t* Gp   = (half_t*)alloc((size_t)KZ * B_ * N3 * 2);     //  9.2 MB fp16
  float*  h0   = (float*)alloc((size_t)B_ * H_ * 4);           // ping-pong h [B][H]
  float*  h1   = (float*)alloc((size_t)B_ * H_ * 4);
  half_t* Ap0  = (half_t*)alloc((size_t)B_ * H_ * 2);          // packed hh
  half_t* Ap1  = (half_t*)alloc((size_t)B_ * H_ * 2);

  gather_cast_x<<<(B_ * S_ * EP) / 256, 256, 0, stream>>>(tokens, emb, xb);
  convert_wi<<<(N3 * EP) / 256, 256, 0, stream>>>(Wir, Wii, Win, bir, bii, bin, Wi, bias);
  convert_wh<<<(N3 * KH) / 256, 256, 0, stream>>>(Whr, Whi, Whn, Wp);
  init_h<<<(B_ * H_) / 256, 256, 0, stream>>>(h0, Ap0);

  // Phase 1: gates_x = fp16( x @ W_i^T + b )   [6144 x 7200]
  gemm_x<<<dim3(48, 57), 256, 0, stream>>>(xb, Wi, gx, bias);

  // Phase 2: 48 GRU steps x {250-block LDS-staged GEMM, 300-block gate}
  for (int t = 0; t < S_; ++t) {
    const half_t* ai = (t & 1) ? Ap1 : Ap0;
    half_t*       aw = (t & 1) ? Ap0 : Ap1;
    const float*  ho = (t & 1) ? h1  : h0;
    float*        hn = (t & 1) ? h0  : h1;
    gru_gemm<<<dim3(NG, KZ), 768, 0, stream>>>(ai, Wp, Gp);
    gru_gate<<<(B_ * H_ / 4) / 256, 256, 0, stream>>>(
        Gp, gx, ho, hn, aw, lengths, out, t);
  }
}